// Round 16
// baseline (144.295 us; speedup 1.0000x reference)
//
#include <hip/hip_runtime.h>
#include <hip/hip_fp16.h>

#define B_HIST 512   // blocks in hist/scatter phases (must match both)
#define SHIFT  9     // coarse bucket = dst >> 9 (512 nodes/bucket); NB <= 256 for N <= 131072

typedef _Float16 f16x8 __attribute__((ext_vector_type(8)));
typedef float f32x4 __attribute__((ext_vector_type(4)));
typedef float f32x2 __attribute__((ext_vector_type(2)));

#define FP8_SCALE 32.0f
#define FP8_INV   (1.0f / 32.0f)

// ================= CSR build: two-level counting sort, LDS atomics only =================

__global__ __launch_bounds__(256) void p1_hist(const int* __restrict__ dst,
                                               int* __restrict__ histT, int E) {
  __shared__ int h[256];
  const int t = threadIdx.x;
  h[t] = 0;
  __syncthreads();
  const int epb = (E + B_HIST - 1) / B_HIST;
  const int beg = blockIdx.x * epb;
  const int end = min(beg + epb, E);
  for (int e = beg + t; e < end; e += 256)
    atomicAdd(&h[dst[e] >> SHIFT], 1);          // LDS atomic
  __syncthreads();
  histT[t * B_HIST + blockIdx.x] = h[t];
}

__global__ __launch_bounds__(256) void p2a_colscan(int* __restrict__ histT,
                                                   int* __restrict__ bsum) {
  __shared__ int sdata[256];
  const int bin = blockIdx.x, t = threadIdx.x;
  const int i0 = bin * B_HIST + 2 * t;
  int c0 = histT[i0], c1 = histT[i0 + 1];
  int s = c0 + c1;
  sdata[t] = s;
  __syncthreads();
  for (int off = 1; off < 256; off <<= 1) {
    int x = 0;
    if (t >= off) x = sdata[t - off];
    __syncthreads();
    if (t >= off) sdata[t] += x;
    __syncthreads();
  }
  int excl = sdata[t] - s;
  histT[i0] = excl;
  histT[i0 + 1] = excl + c0;
  if (t == 255) bsum[bin] = sdata[255];
}

__global__ __launch_bounds__(256) void p2b_scan(const int* __restrict__ bsum,
                                                int* __restrict__ colstart) {
  __shared__ int sdata[256];
  const int t = threadIdx.x;
  int v = bsum[t];
  sdata[t] = v;
  __syncthreads();
  for (int off = 1; off < 256; off <<= 1) {
    int x = 0;
    if (t >= off) x = sdata[t - off];
    __syncthreads();
    if (t >= off) sdata[t] += x;
    __syncthreads();
  }
  colstart[t] = sdata[t] - v;
  if (t == 255) colstart[256] = sdata[255];
}

__global__ __launch_bounds__(256) void p3_scatter(const int* __restrict__ src,
                                                  const int* __restrict__ dst,
                                                  const int* __restrict__ histT,
                                                  const int* __restrict__ colstart,
                                                  int* __restrict__ pbuf, int E) {
  __shared__ int cur[256];
  const int t = threadIdx.x;
  cur[t] = colstart[t] + histT[t * B_HIST + blockIdx.x];
  __syncthreads();
  const int epb = (E + B_HIST - 1) / B_HIST;
  const int beg = blockIdx.x * epb;
  const int end = min(beg + epb, E);
  for (int e = beg + t; e < end; e += 256) {
    int d = dst[e];
    int s = src[e];
    int pos = atomicAdd(&cur[d >> SHIFT], 1);   // LDS atomic
    pbuf[pos] = ((d & 511) << 17) | s;
  }
}

// P4: per-bucket fine counting sort -> rowptr, dinv, ssrc
__global__ __launch_bounds__(256) void p4_fine(const int* __restrict__ pbuf,
                                               const int* __restrict__ colstart,
                                               int* __restrict__ rowptr,
                                               float* __restrict__ dinv,
                                               int* __restrict__ ssrc, int N, int NB) {
  __shared__ int cnt[512];
  __shared__ int sdata[256];
  __shared__ int cur[512];
  const int b = blockIdx.x, t = threadIdx.x;
  const int base = colstart[b], endp = colstart[b + 1];
  cnt[2 * t] = 0; cnt[2 * t + 1] = 0;
  __syncthreads();
  for (int i = base + t; i < endp; i += 256)
    atomicAdd(&cnt[pbuf[i] >> 17], 1);
  __syncthreads();
  int c0 = cnt[2 * t], c1 = cnt[2 * t + 1];
  int s = c0 + c1;
  sdata[t] = s;
  __syncthreads();
  for (int off = 1; off < 256; off <<= 1) {
    int x = 0;
    if (t >= off) x = sdata[t - off];
    __syncthreads();
    if (t >= off) sdata[t] += x;
    __syncthreads();
  }
  int excl = sdata[t] - s;
  int e0 = base + excl, e1 = base + excl + c0;
  cur[2 * t] = e0;
  cur[2 * t + 1] = e1;
  int node0 = (b << SHIFT) + 2 * t;
  if (node0 < N) {
    rowptr[node0] = e0;
    dinv[node0] = rsqrtf((float)c0 + 1.0f);
  }
  if (node0 + 1 < N) {
    rowptr[node0 + 1] = e1;
    dinv[node0 + 1] = rsqrtf((float)c1 + 1.0f);
  }
  if (b == NB - 1 && t == 0) rowptr[N] = endp;
  __syncthreads();
  for (int i = base + t; i < endp; i += 256) {
    int p = pbuf[i];
    int pos = atomicAdd(&cur[p >> 17], 1);      // LDS atomic
    ssrc[pos] = p & 0x1FFFF;
  }
}

// ============ W pre-pack: fp32 W[K][COLS] -> fp16 B-fragments ((kq)*COLS+col)*8+j ============

template <int COLS, int K>
__global__ __launch_bounds__(256) void wpack_kernel(const float* __restrict__ W,
                                                    _Float16* __restrict__ P) {
  int task = blockIdx.x * 256 + threadIdx.x;
  if (task >= (K / 8) * COLS) return;
  int col = task % COLS;
  int kq = task / COLS;
  _Float16 tmp[8];
#pragma unroll
  for (int j = 0; j < 8; ++j)
    tmp[j] = (_Float16)W[(kq * 8 + j) * COLS + col];
  *reinterpret_cast<f16x8*>(&P[task * 8]) = *reinterpret_cast<const f16x8*>(tmp);
}

// ========== MFMA GEMM: O[N][COLS] (*dinv) = X[N][K] @ Wpacked ==========
// FP8_OUT: O = fp8 e4m3 bytes, scaled by FP8_SCALE. Else fp16.

template <int COLS, int K, typename XT, bool FP8_OUT>
__global__ __launch_bounds__(256) void mfma_gemm(const XT* __restrict__ X,
                                                 const _Float16* __restrict__ wpk,
                                                 const float* __restrict__ dinv,
                                                 void* __restrict__ O, int N) {
  constexpr int NKK = K / 32;        // MFMA K-steps
  constexpr int NCT = COLS / 16;     // col tiles
  constexpr int RCH = K / 8;         // 16B fp16 chunks per row
  constexpr int SWM = RCH - 1;       // chunk swizzle mask
  __shared__ _Float16 xs[64 * K];
  __shared__ _Float16 wb[K * COLS];  // packed B-frags (copied from wpk)
  const int t = threadIdx.x;
  const int row0 = blockIdx.x * 64;

  for (int i = t; i < K * COLS / 8; i += 256)
    *reinterpret_cast<f16x8*>(&wb[i * 8]) = reinterpret_cast<const f16x8*>(wpk)[i];
  for (int task = t; task < 64 * RCH; task += 256) {
    int row = task / RCH, c = task % RCH;
    int grow = row0 + row;
    f16x8 hv;
#pragma unroll
    for (int j = 0; j < 8; ++j) hv[j] = (_Float16)0.f;
    if (grow < N) {
      if constexpr (sizeof(XT) == 4) {
        const float4* xr = reinterpret_cast<const float4*>(X + (size_t)grow * K);
        float4 v0 = xr[c * 2], v1 = xr[c * 2 + 1];
        hv[0] = (_Float16)v0.x; hv[1] = (_Float16)v0.y;
        hv[2] = (_Float16)v0.z; hv[3] = (_Float16)v0.w;
        hv[4] = (_Float16)v1.x; hv[5] = (_Float16)v1.y;
        hv[6] = (_Float16)v1.z; hv[7] = (_Float16)v1.w;
      } else {
        hv = reinterpret_cast<const f16x8*>(X + (size_t)grow * K)[c];
      }
    }
    int sc = c ^ (row & SWM);
    *reinterpret_cast<f16x8*>(&xs[row * K + sc * 8]) = hv;
  }
  __syncthreads();

  const int wave = t >> 6, lane = t & 63;
  const int q = lane >> 4, c = lane & 15;
  const int wrow = wave * 16;

  f16x8 bfrag[NKK][NCT];
#pragma unroll
  for (int kk = 0; kk < NKK; ++kk)
#pragma unroll
    for (int ct = 0; ct < NCT; ++ct)
      bfrag[kk][ct] = *reinterpret_cast<const f16x8*>(
          &wb[(size_t)((kk * 4 + q) * COLS + ct * 16 + c) * 8]);

  f32x4 acc[NCT];
#pragma unroll
  for (int ct = 0; ct < NCT; ++ct) acc[ct] = {0.f, 0.f, 0.f, 0.f};

#pragma unroll
  for (int kk = 0; kk < NKK; ++kk) {
    int row = wrow + c;
    int cc = (kk * 4 + q) ^ (row & SWM);
    f16x8 afrag = *reinterpret_cast<const f16x8*>(&xs[row * K + cc * 8]);
#pragma unroll
    for (int ct = 0; ct < NCT; ++ct)
      acc[ct] = __builtin_amdgcn_mfma_f32_16x16x32_f16(afrag, bfrag[kk][ct], acc[ct], 0, 0, 0);
  }

#pragma unroll
  for (int r = 0; r < 4; ++r) {
    int row = row0 + wrow + q * 4 + r;
    if (row < N) {
      float di = dinv[row];
#pragma unroll
      for (int ct = 0; ct < NCT; ++ct) {
        int col = ct * 16 + c;
        if constexpr (FP8_OUT) {
          float v = acc[ct][r] * di * FP8_SCALE;
          int pk = __builtin_amdgcn_cvt_pk_fp8_f32(v, v, 0, false);
          ((unsigned char*)O)[(size_t)row * COLS + col] = (unsigned char)(pk & 0xFF);
        } else {
          ((__half*)O)[(size_t)row * COLS + col] = __float2half(acc[ct][r] * di);
        }
      }
    }
  }
}

// ====== layer-1 gather: fp8 table, DUAL node-chains per 16-lane group (ILP x2) ======
__global__ __launch_bounds__(256) void gather64_fp8_kernel(const int* __restrict__ rowptr,
                                                           const int* __restrict__ ssrc,
                                                           const float* __restrict__ dinv,
                                                           const unsigned int* __restrict__ g8,
                                                           const float4* __restrict__ bias,
                                                           __half* __restrict__ outb, int N) {
  int gid = (blockIdx.x * 256 + threadIdx.x) >> 4;
  int col = threadIdx.x & 15;
  int nodeA = 2 * gid;
  if (nodeA >= N) return;
  int nodeB = nodeA + 1;
  bool hasB = nodeB < N;
  int begA = rowptr[nodeA];
  int endA = rowptr[nodeA + 1];
  int endB = hasB ? rowptr[nodeB + 1] : endA;
  int begB = endA;                 // rowptr[nodeB] == rowptr[nodeA+1]
  unsigned int selfA = g8[(size_t)nodeA * 16 + col];
  unsigned int selfB = hasB ? g8[(size_t)nodeB * 16 + col] : 0u;

  float4 a0A = {0.f, 0.f, 0.f, 0.f}, a1A = a0A, a0B = a0A, a1B = a0A;
  int iA = begA, iB = begB;
  while (iA < endA || iB < endB) {
    int mA = endA - iA, mB = endB - iB;
    int svA = 0, svB = 0;
    if (col < mA) svA = ssrc[iA + col];
    if (col < mB) svB = ssrc[iB + col];
    unsigned int vA[16], vB[16];
#pragma unroll
    for (int u = 0; u < 16; ++u) {
      if (u < mA) vA[u] = g8[(size_t)__shfl(svA, u, 16) * 16 + col];
      if (u < mB) vB[u] = g8[(size_t)__shfl(svB, u, 16) * 16 + col];
    }
#pragma unroll
    for (int u = 0; u < 16; ++u) {
      if (u < mA) {
        f32x2 lo = __builtin_amdgcn_cvt_pk_f32_fp8((int)vA[u], false);
        f32x2 hi = __builtin_amdgcn_cvt_pk_f32_fp8((int)vA[u], true);
        float4& a = (u & 1) ? a1A : a0A;
        a.x += lo.x; a.y += lo.y; a.z += hi.x; a.w += hi.y;
      }
      if (u < mB) {
        f32x2 lo = __builtin_amdgcn_cvt_pk_f32_fp8((int)vB[u], false);
        f32x2 hi = __builtin_amdgcn_cvt_pk_f32_fp8((int)vB[u], true);
        float4& a = (u & 1) ? a1B : a0B;
        a.x += lo.x; a.y += lo.y; a.z += hi.x; a.w += hi.y;
      }
    }
    iA += 16; iB += 16;
  }
  float4 bb = bias[col];
  {
    f32x2 slo = __builtin_amdgcn_cvt_pk_f32_fp8((int)selfA, false);
    f32x2 shi = __builtin_amdgcn_cvt_pk_f32_fp8((int)selfA, true);
    float inv = dinv[nodeA] * FP8_INV;
    float ox = fmaxf(fmaf(inv, a0A.x + a1A.x + slo.x, bb.x), 0.f);
    float oy = fmaxf(fmaf(inv, a0A.y + a1A.y + slo.y, bb.y), 0.f);
    float oz = fmaxf(fmaf(inv, a0A.z + a1A.z + shi.x, bb.z), 0.f);
    float ow = fmaxf(fmaf(inv, a0A.w + a1A.w + shi.y, bb.w), 0.f);
    union { __half2 h2[2]; uint2 u; } cv;
    cv.h2[0] = __floats2half2_rn(ox, oy);
    cv.h2[1] = __floats2half2_rn(oz, ow);
    reinterpret_cast<uint2*>(outb)[(size_t)nodeA * 16 + col] = cv.u;
  }
  if (hasB) {
    f32x2 slo = __builtin_amdgcn_cvt_pk_f32_fp8((int)selfB, false);
    f32x2 shi = __builtin_amdgcn_cvt_pk_f32_fp8((int)selfB, true);
    float inv = dinv[nodeB] * FP8_INV;
    float ox = fmaxf(fmaf(inv, a0B.x + a1B.x + slo.x, bb.x), 0.f);
    float oy = fmaxf(fmaf(inv, a0B.y + a1B.y + slo.y, bb.y), 0.f);
    float oz = fmaxf(fmaf(inv, a0B.z + a1B.z + shi.x, bb.z), 0.f);
    float ow = fmaxf(fmaf(inv, a0B.w + a1B.w + shi.y, bb.w), 0.f);
    union { __half2 h2[2]; uint2 u; } cv;
    cv.h2[0] = __floats2half2_rn(ox, oy);
    cv.h2[1] = __floats2half2_rn(oz, ow);
    reinterpret_cast<uint2*>(outb)[(size_t)nodeB * 16 + col] = cv.u;
  }
}

// ====== layer-2 gather: fp16 table, DUAL node-chains per 8-lane group ======
__global__ __launch_bounds__(256) void gather32_kernel(const int* __restrict__ rowptr,
                                                       const int* __restrict__ ssrc,
                                                       const float* __restrict__ dinv,
                                                       const uint2* __restrict__ g,
                                                       const float4* __restrict__ bias,
                                                       float4* __restrict__ outb, int N) {
  int gid = (blockIdx.x * 256 + threadIdx.x) >> 3;
  int col = threadIdx.x & 7;
  int nodeA = 2 * gid;
  if (nodeA >= N) return;
  int nodeB = nodeA + 1;
  bool hasB = nodeB < N;
  int begA = rowptr[nodeA];
  int endA = rowptr[nodeA + 1];
  int endB = hasB ? rowptr[nodeB + 1] : endA;
  int begB = endA;
  uint2 selfA = g[(size_t)nodeA * 8 + col];
  uint2 selfB = hasB ? g[(size_t)nodeB * 8 + col] : make_uint2(0u, 0u);

  float4 a0A = {0.f, 0.f, 0.f, 0.f}, a1A = a0A, a0B = a0A, a1B = a0A;
  int iA = begA, iB = begB;
  while (iA < endA || iB < endB) {
    int mA = endA - iA, mB = endB - iB;
    int svA = 0, svB = 0;
    if (col < mA) svA = ssrc[iA + col];
    if (col < mB) svB = ssrc[iB + col];
    uint2 vA[8], vB[8];
#pragma unroll
    for (int u = 0; u < 8; ++u) {
      if (u < mA) vA[u] = g[(size_t)__shfl(svA, u, 8) * 8 + col];
      if (u < mB) vB[u] = g[(size_t)__shfl(svB, u, 8) * 8 + col];
    }
#pragma unroll
    for (int u = 0; u < 8; ++u) {
      if (u < mA) {
        float2 f0 = __half22float2(*(__half2*)&vA[u].x);
        float2 f1 = __half22float2(*(__half2*)&vA[u].y);
        float4& a = (u & 1) ? a1A : a0A;
        a.x += f0.x; a.y += f0.y; a.z += f1.x; a.w += f1.y;
      }
      if (u < mB) {
        float2 f0 = __half22float2(*(__half2*)&vB[u].x);
        float2 f1 = __half22float2(*(__half2*)&vB[u].y);
        float4& a = (u & 1) ? a1B : a0B;
        a.x += f0.x; a.y += f0.y; a.z += f1.x; a.w += f1.y;
      }
    }
    iA += 8; iB += 8;
  }
  float4 bb = bias[col];
  {
    float2 g01 = __half22float2(*(__half2*)&selfA.x);
    float2 g23 = __half22float2(*(__half2*)&selfA.y);
    float di = dinv[nodeA];
    float4 o;
    o.x = fmaf(di, a0A.x + a1A.x + g01.x, bb.x);
    o.y = fmaf(di, a0A.y + a1A.y + g01.y, bb.y);
    o.z = fmaf(di, a0A.z + a1A.z + g23.x, bb.z);
    o.w = fmaf(di, a0A.w + a1A.w + g23.y, bb.w);
    outb[(size_t)nodeA * 8 + col] = o;
  }
  if (hasB) {
    float2 g01 = __half22float2(*(__half2*)&selfB.x);
    float2 g23 = __half22float2(*(__half2*)&selfB.y);
    float di = dinv[nodeB];
    float4 o;
    o.x = fmaf(di, a0B.x + a1B.x + g01.x, bb.x);
    o.y = fmaf(di, a0B.y + a1B.y + g01.y, bb.y);
    o.z = fmaf(di, a0B.z + a1B.z + g23.x, bb.z);
    o.w = fmaf(di, a0B.w + a1B.w + g23.y, bb.w);
    outb[(size_t)nodeB * 8 + col] = o;
  }
}

// ================= launch =================

extern "C" void kernel_launch(void* const* d_in, const int* in_sizes, int n_in,
                              void* d_out, int out_size, void* d_ws, size_t ws_size,
                              hipStream_t stream) {
  const float* x  = (const float*)d_in[0];
  const int*   ei = (const int*)d_in[1];
  const float* W1 = (const float*)d_in[2];
  const float* b1 = (const float*)d_in[3];
  const float* W2 = (const float*)d_in[4];
  const float* b2 = (const float*)d_in[5];
  float* out = (float*)d_out;

  const int H = in_sizes[3];            // 64
  const int F = in_sizes[2] / H;        // 128
  const int N = in_sizes[0] / F;        // 100000
  const int E = in_sizes[1] / 2;        // 1600000
  const int* src = ei;
  const int* dst = ei + E;
  const int NB = (N + 511) >> SHIFT;    // coarse buckets (196 for N=100k)

  char* w = (char*)d_ws;
  auto alloc = [&](size_t bytes) { char* p = w; w += (bytes + 255) & ~(size_t)255; return p; };
  int*           histT    = (int*)alloc((size_t)256 * B_HIST * 4);
  int*           bsum     = (int*)alloc(256 * 4);
  int*           colstart = (int*)alloc(257 * 4);
  int*           pbuf     = (int*)alloc((size_t)E * 4);
  int*           ssrc     = (int*)alloc((size_t)E * 4);
  int*           rowptr   = (int*)alloc((size_t)(N + 1) * 4);
  float*         dinv     = (float*)alloc((size_t)N * 4);
  _Float16*      wp1      = (_Float16*)alloc((size_t)128 * 64 * 2);
  _Float16*      wp2      = (_Float16*)alloc((size_t)64 * 32 * 2);
  unsigned char* g1q      = (unsigned char*)alloc((size_t)N * 64);  // fp8 e4m3, scaled
  __half*        buf1     = (__half*)alloc((size_t)N * 64 * 2);
  __half*        g2       = (__half*)alloc((size_t)N * 32 * 2);

  // W pre-pack (tiny, independent)
  wpack_kernel<64, 128><<<4, 256, 0, stream>>>(W1, wp1);
  wpack_kernel<32, 64><<<1, 256, 0, stream>>>(W2, wp2);

  // CSR build (no global atomics)
  p1_hist<<<B_HIST, 256, 0, stream>>>(dst, histT, E);
  p2a_colscan<<<256, 256, 0, stream>>>(histT, bsum);
  p2b_scan<<<1, 256, 0, stream>>>(bsum, colstart);
  p3_scatter<<<B_HIST, 256, 0, stream>>>(src, dst, histT, colstart, pbuf, E);
  p4_fine<<<NB, 256, 0, stream>>>(pbuf, colstart, rowptr, dinv, ssrc, N, NB);

  const int ngrp = (N + 1) / 2;         // dual-node groups

  // layer 1: g1q = fp8(S * dinv .* (x @ W1))
  mfma_gemm<64, 128, float, true><<<(N + 63) / 64, 256, 0, stream>>>(x, wp1, dinv, g1q, N);
  gather64_fp8_kernel<<<(ngrp * 16 + 255) / 256, 256, 0, stream>>>(rowptr, ssrc, dinv,
      (const unsigned int*)g1q, (const float4*)b1, buf1, N);

  // layer 2: g2 = dinv .* (r1 @ W2)  (fp16 MFMA, fp16 input)
  mfma_gemm<32, 64, _Float16, false><<<(N + 63) / 64, 256, 0, stream>>>(
      (const _Float16*)buf1, wp2, dinv, g2, N);
  gather32_kernel<<<(ngrp * 8 + 255) / 256, 256, 0, stream>>>(rowptr, ssrc, dinv,
      (const uint2*)g2, (const float4*)b2, (float4*)out, N);
}